// Round 3
// baseline (127.704 us; speedup 1.0000x reference)
//
#include <hip/hip_runtime.h>

// LIF recurrence: T=128 timesteps, N neurons (fp32).
//   v = BETA*v + I[t] - GAMMA*s ;  s = (v > 1) ;  v = v*(1-s)
// Outputs concatenated flat: spikes (T*N) | v_mem (T*N) | spikes (T*N).
//
// Memory-bound: 134 MB read + 403 MB write. Round-1 (float4/thread, 1 wave/
// SIMD) hit 102 us = 5.26 TB/s. This round: float2/thread doubles wave count
// (2 waves/SIMD) for latency hiding on the mixed 1R:3W stream, and
// non-temporal loads/stores skip cache allocation for streamed-once data.
// (__builtin_nontemporal_* needs clang ext_vector types, not HIP float2.)
//
// NOTE: spike threshold (v > 1.0f) is a hard decision boundary. To match the
// numpy reference bit-exactly we replicate its per-op fp32 rounding:
// ((BETA*v + I) - GAMMA*s) with NO fma contraction (__fmul_rn/__fadd_rn/
// __fsub_rn). The reset v*(1-s) is exactly (s ? 0 : v) since s is 0 or 1.

#define T_STEPS 128
#define BETA_F 0.95f
#define GAMMA_F 0.95f
#define VTH_F 1.0f

typedef float f32x2 __attribute__((ext_vector_type(2)));

__global__ __launch_bounds__(256) void lif_kernel(
    const f32x2* __restrict__ I2,
    f32x2* __restrict__ s_out,   // spikes, first copy
    f32x2* __restrict__ v_out,   // v_mem
    f32x2* __restrict__ s_out2,  // spikes, second copy
    int n2)                      // N/2
{
    int idx = blockIdx.x * blockDim.x + threadIdx.x;
    if (idx >= n2) return;

    float vx = 0.f, vy = 0.f;
    float sx = 0.f, sy = 0.f;

    size_t off = (size_t)idx;
    #pragma unroll 8
    for (int t = 0; t < T_STEPS; ++t, off += (size_t)n2) {
        f32x2 in = __builtin_nontemporal_load(&I2[off]);

        // v = (BETA*v + I) - GAMMA*s, numpy-exact per-op rounding
        vx = __fsub_rn(__fadd_rn(__fmul_rn(BETA_F, vx), in.x), __fmul_rn(GAMMA_F, sx));
        vy = __fsub_rn(__fadd_rn(__fmul_rn(BETA_F, vy), in.y), __fmul_rn(GAMMA_F, sy));

        sx = (vx > VTH_F) ? 1.0f : 0.0f;
        sy = (vy > VTH_F) ? 1.0f : 0.0f;

        // hard reset: v*(1-s) == (s ? 0 : v) exactly
        vx = (sx != 0.0f) ? 0.0f : vx;
        vy = (sy != 0.0f) ? 0.0f : vy;

        f32x2 sv; sv.x = sx; sv.y = sy;
        f32x2 vv; vv.x = vx; vv.y = vy;
        __builtin_nontemporal_store(sv, &s_out[off]);
        __builtin_nontemporal_store(vv, &v_out[off]);
        __builtin_nontemporal_store(sv, &s_out2[off]);
    }
}

extern "C" void kernel_launch(void* const* d_in, const int* in_sizes, int n_in,
                              void* d_out, int out_size, void* d_ws, size_t ws_size,
                              hipStream_t stream) {
    const float* I = (const float*)d_in[0];
    float* out = (float*)d_out;

    const int TN = in_sizes[0];        // T * N
    const int N = TN / T_STEPS;
    const int n2 = N / 2;

    float* s0 = out;
    float* vm = out + (size_t)TN;
    float* s1 = out + 2 * (size_t)TN;

    const int block = 256;
    const int grid = (n2 + block - 1) / block;

    lif_kernel<<<grid, block, 0, stream>>>(
        (const f32x2*)I, (f32x2*)s0, (f32x2*)vm, (f32x2*)s1, n2);
}

// Round 4
// 75.591 us; speedup vs baseline: 1.6894x; 1.6894x over previous
//
#include <hip/hip_runtime.h>

// LIF recurrence: T=128 timesteps, N neurons (fp32).
//   v = BETA*v + I[t] - GAMMA*s ;  s = (v > 1) ;  v = v*(1-s)
// Outputs concatenated flat: spikes (T*N) | v_mem (T*N) | spikes (T*N).
//
// Round-1 (float4/thread, plain loads+stores): 102 us = 5.26 TB/s combined.
// Round-3 (float2 + nt loads + nt stores): 127.7 us — REGRESSED, unattributed.
// Round-4 isolates: exact round-1 float4 structure, ONLY stores are
// non-temporal (output is written-once-never-read; keep it out of cache so
// the 134 MB input can stay resident in the 256 MB L3 across replays).
// Load stays plain (cacheable) on purpose.
//
// NOTE: spike threshold (v > 1.0f) is a hard decision boundary. To match the
// numpy reference bit-exactly we replicate its per-op fp32 rounding:
// ((BETA*v + I) - GAMMA*s) with NO fma contraction (__fmul_rn/__fadd_rn/
// __fsub_rn). The reset v*(1-s) is exactly (s ? 0 : v) since s is 0 or 1.

#define T_STEPS 128
#define BETA_F 0.95f
#define GAMMA_F 0.95f
#define VTH_F 1.0f

typedef float f32x4 __attribute__((ext_vector_type(4)));

__global__ __launch_bounds__(256) void lif_kernel(
    const f32x4* __restrict__ I4,
    f32x4* __restrict__ s_out,   // spikes, first copy
    f32x4* __restrict__ v_out,   // v_mem
    f32x4* __restrict__ s_out2,  // spikes, second copy
    int n4)                      // N/4
{
    int idx = blockIdx.x * blockDim.x + threadIdx.x;
    if (idx >= n4) return;

    float vx = 0.f, vy = 0.f, vz = 0.f, vw = 0.f;
    float sx = 0.f, sy = 0.f, sz = 0.f, sw = 0.f;

    size_t off = (size_t)idx;
    #pragma unroll 8
    for (int t = 0; t < T_STEPS; ++t, off += (size_t)n4) {
        f32x4 in = I4[off];   // plain (cacheable) load

        // v = (BETA*v + I) - GAMMA*s, numpy-exact per-op rounding
        vx = __fsub_rn(__fadd_rn(__fmul_rn(BETA_F, vx), in.x), __fmul_rn(GAMMA_F, sx));
        vy = __fsub_rn(__fadd_rn(__fmul_rn(BETA_F, vy), in.y), __fmul_rn(GAMMA_F, sy));
        vz = __fsub_rn(__fadd_rn(__fmul_rn(BETA_F, vz), in.z), __fmul_rn(GAMMA_F, sz));
        vw = __fsub_rn(__fadd_rn(__fmul_rn(BETA_F, vw), in.w), __fmul_rn(GAMMA_F, sw));

        sx = (vx > VTH_F) ? 1.0f : 0.0f;
        sy = (vy > VTH_F) ? 1.0f : 0.0f;
        sz = (vz > VTH_F) ? 1.0f : 0.0f;
        sw = (vw > VTH_F) ? 1.0f : 0.0f;

        // hard reset: v*(1-s) == (s ? 0 : v) exactly
        vx = (sx != 0.0f) ? 0.0f : vx;
        vy = (sy != 0.0f) ? 0.0f : vy;
        vz = (sz != 0.0f) ? 0.0f : vz;
        vw = (sw != 0.0f) ? 0.0f : vw;

        f32x4 sv; sv.x = sx; sv.y = sy; sv.z = sz; sv.w = sw;
        f32x4 vv; vv.x = vx; vv.y = vy; vv.z = vz; vv.w = vw;
        __builtin_nontemporal_store(sv, &s_out[off]);
        __builtin_nontemporal_store(vv, &v_out[off]);
        __builtin_nontemporal_store(sv, &s_out2[off]);
    }
}

extern "C" void kernel_launch(void* const* d_in, const int* in_sizes, int n_in,
                              void* d_out, int out_size, void* d_ws, size_t ws_size,
                              hipStream_t stream) {
    const float* I = (const float*)d_in[0];
    float* out = (float*)d_out;

    const int TN = in_sizes[0];        // T * N
    const int N = TN / T_STEPS;
    const int n4 = N / 4;

    float* s0 = out;
    float* vm = out + (size_t)TN;
    float* s1 = out + 2 * (size_t)TN;

    const int block = 256;
    const int grid = (n4 + block - 1) / block;

    lif_kernel<<<grid, block, 0, stream>>>(
        (const f32x4*)I, (f32x4*)s0, (f32x4*)vm, (f32x4*)s1, n4);
}